// Round 4
// baseline (245.641 us; speedup 1.0000x reference)
//
#include <hip/hip_runtime.h>

// Problem constants (from reference setup_inputs):
//   x: (1, 3, 128, 128) fp32
//   w: (3, 124, 124, 25, 5, 5) fp32
//   q: (3, 124, 124, 25, 5, 5) fp32
//   out: (1, 3, 124, 124, 25) fp32
// out[o] = log( prod_{k=0..24} (1.1 + atan(10*(x_k*w_k - q_k))/pi) )
//
// R7 design: R5 persistent counted-vmcnt pipeline + R6's non-temporal staging.
// R6 post-mortem: NT (aux=2) on the w/q DMA broke the ~2.6 TB/s L3-hit-path
// wall -- dendrite dropped 87 -> <67us (out of rocprof top-5; the 67us
// fillBufferAligned resets now dominate, themselves proving 6.8 TB/s HBM).
// Remaining gap to the 37us stream floor (235 MB @ 6.3 TB/s): R6 still does
// issue -> vmcnt(0) DRAIN -> compute -> block dies, ~17.6 block-quanta/CU.
// R5's persistent structure removes all drains/launch bubbles but was tested
// only under the pre-NT wall (92 vs 87us: structure was masked). Post-NT the
// delivery arithmetic says the pipeline wins: 51.2 KB/tile at ~10 B/cyc/CU
// HBM share = 5000 cyc delivery vs ~1200 cyc compute; dbuf + vmcnt(14)
// (never 0 in the loop) keeps the DMA queue continuously full.

#define IMG    128
#define OUT    124
#define NUM    25
#define NOUT   (3 * OUT * OUT * NUM)        // 1,153,200 outputs
#define OPB    256                          // threads per block = outputs per tile
#define NTILES ((NOUT + OPB - 1) / OPB)     // 4505
#define PBLK   256                          // persistent blocks: 1 per CU (LDS-forced)
#define TILEF  (OPB * NUM)                  // 6400 floats per array per tile
#define WQF    (NOUT * NUM)                 // 28,830,000 floats in w (and in q)

// Minimax atan, |err| ~ 2e-6 over all inputs. Range-reduce with v_rcp_f32.
__device__ __forceinline__ float fast_atan(float z) {
    float az  = __builtin_fabsf(z);
    float r   = __builtin_amdgcn_rcpf(az);
    bool  big = az > 1.0f;
    float t   = big ? r : az;                   // t in [0, 1]
    float s   = t * t;
    float p   =                     -0.01172120f;
    p = __builtin_fmaf(p, s,         0.05265332f);
    p = __builtin_fmaf(p, s,        -0.11643287f);
    p = __builtin_fmaf(p, s,         0.19354346f);
    p = __builtin_fmaf(p, s,        -0.33262347f);
    p = __builtin_fmaf(p, s,         0.99997726f);
    float a = t * p;
    a = big ? (1.57079632679489662f - a) : a;
    return __builtin_copysignf(a, z);
}

// Async global->LDS, NON-TEMPORAL (aux=2 -> `nt`: evict-first in L2/MALL; w/q
// have zero reuse, caching them was the R0-R5 bottleneck). LDS dest =
// wave-uniform base + lane*size (HW semantics); global src per-lane.
__device__ __forceinline__ void copy16_lds_nt(const float* g, float* l) {
    __builtin_amdgcn_global_load_lds(
        (const __attribute__((address_space(1))) unsigned int*)g,
        (__attribute__((address_space(3))) unsigned int*)l, 16, 0, 2);
}
__device__ __forceinline__ void copy4_lds_nt(const float* g, float* l) {
    __builtin_amdgcn_global_load_lds(
        (const __attribute__((address_space(1))) unsigned int*)g,
        (__attribute__((address_space(3))) unsigned int*)l, 4, 0, 2);
}

// Stage one tile's w+q into LDS: exactly 14 DMA instructions per wave,
// identical count on every wave and every tile (vmcnt arithmetic stays exact).
// Wave stripe = 1600 floats = 6x(64 lanes x 16B) + 1x(64 lanes x 4B).
// Per-lane src clamp keeps the final tile's overhang in-bounds.
__device__ __forceinline__ void stage_tile(
        float* wl, float* ql,
        const float* __restrict__ w, const float* __restrict__ q,
        int tile, int wave_f, int lane)
{
    const int tb = tile * TILEF;
    #pragma unroll
    for (int r = 0; r < 6; ++r) {
        const int f  = wave_f + r * 256;            // wave-uniform float offset
        int sf = tb + f + lane * 4;                 // per-lane src float index
        sf = min(sf, WQF - 4);
        copy16_lds_nt(w + sf, wl + f);
        copy16_lds_nt(q + sf, ql + f);
    }
    const int f  = wave_f + 1536;
    int sf = tb + f + lane;
    sf = min(sf, WQF - 1);
    copy4_lds_nt(w + sf, wl + f);
    copy4_lds_nt(q + sf, ql + f);
}

// Per-thread x patch (5x5 window) -> registers. Lanes in 25-groups share a
// patch; x is 196 KB with heavy reuse: NORMAL cached loads (not NT).
__device__ __forceinline__ void load_x(
        float (&xv)[NUM], const float* __restrict__ x, int o)
{
    const int oc = min(o, NOUT - 1);                // clamp tail addressing
    int rem = oc / NUM;                             // (c*OUT + i)*OUT + j
    const int j = rem % OUT;  rem /= OUT;
    const int i = rem % OUT;
    const int c = rem / OUT;
    const float* xp = x + (c * IMG + i) * IMG + j;
    #pragma unroll
    for (int u = 0; u < 5; ++u) {
        float4 a;
        __builtin_memcpy(&a, xp + u * IMG, sizeof(float4));   // dword-aligned ok
        xv[5*u+0] = a.x; xv[5*u+1] = a.y; xv[5*u+2] = a.z; xv[5*u+3] = a.w;
        xv[5*u+4] = xp[u * IMG + 4];
    }
}

__device__ __forceinline__ float compute25(
        const float* wl, const float* ql, const float (&xv)[NUM])
{
    float prod0 = 1.0f, prod1 = 1.0f;
    #pragma unroll
    for (int k = 0; k < NUM; ++k) {
        const float z = 10.0f * __builtin_fmaf(xv[k], wl[k], -ql[k]);
        const float a = fast_atan(z);
        const float term = __builtin_fmaf(a, 0.31830988618379067f, 1.1f);
        if (k & 1) prod1 *= term; else prod0 *= term;
    }
    // prod in (~0.6^25, ~1.6^25): fp32-safe, single log.
    return __logf(prod0 * prod1);
}

__global__ __launch_bounds__(OPB) void dendrite_kernel(
    const float* __restrict__ x,
    const float* __restrict__ w,
    const float* __restrict__ q,
    float* __restrict__ out)
{
    __shared__ float w_lds[2][TILEF];     // 2 x 25.6 KB
    __shared__ float q_lds[2][TILEF];     // 2 x 25.6 KB  (100 KiB -> 1 block/CU)

    const int tid    = threadIdx.x;
    const int lane   = tid & 63;
    const int wave_f = (tid >> 6) * 1600;   // per-wave staging stripe (floats)

    // One pipeline step: compute tile t from (wl,ql,xc); prefetch tile t+PBLK
    // into (wln,qln,xn). vmcnt(14) = "wait for everything except the 14 DMA
    // just issued": tile t's DMA are OLDER than the x loads/store issued after
    // them, so draining to 14 completes all of tile t while tile t+1's 51.2 KB
    // stays in flight across the raw s_barrier (never __syncthreads -- that
    // would emit the vmcnt(0) drain this design exists to avoid).
    auto step = [&](const float* wl, const float* ql, float* wln, float* qln,
                    float (&xc)[NUM], float (&xn)[NUM], int t) {
        const int  tnext    = t + PBLK;
        const bool has_next = (tnext < NTILES);          // wave-uniform
        __builtin_amdgcn_s_barrier();                    // next buf free to overwrite
        if (has_next) {
            stage_tile(wln, qln, w, q, tnext, wave_f, lane);
            asm volatile("s_waitcnt vmcnt(14)" ::: "memory");
        } else {
            asm volatile("s_waitcnt vmcnt(0)" ::: "memory");
        }
        __builtin_amdgcn_s_barrier();                    // tile t visible block-wide
        const int o = t * OPB + tid;
        if (has_next) load_x(xn, x, o + PBLK * OPB);     // latency hides under compute
        if (o < NOUT)
            __builtin_nontemporal_store(
                compute25(&wl[tid * NUM], &ql[tid * NUM], xc), &out[o]);
    };

    // Prologue: stage first tile, load its x patch.
    int t = blockIdx.x;
    float xA[NUM], xB[NUM];
    stage_tile(w_lds[0], q_lds[0], w, q, t, wave_f, lane);
    load_x(xA, x, t * OPB + tid);

    // Steady loop: 2 steps per iteration for static register double-buffering.
    for (;;) {
        step(w_lds[0], q_lds[0], w_lds[1], q_lds[1], xA, xB, t);
        t += PBLK;
        if (t >= NTILES) break;
        step(w_lds[1], q_lds[1], w_lds[0], q_lds[0], xB, xA, t);
        t += PBLK;
        if (t >= NTILES) break;
    }
}

extern "C" void kernel_launch(void* const* d_in, const int* in_sizes, int n_in,
                              void* d_out, int out_size, void* d_ws, size_t ws_size,
                              hipStream_t stream) {
    const float* x = (const float*)d_in[0];
    const float* w = (const float*)d_in[1];
    const float* q = (const float*)d_in[2];
    float* out = (float*)d_out;

    dendrite_kernel<<<PBLK, OPB, 0, stream>>>(x, w, q, out);   // 256 persistent blocks
}